// Round 7
// baseline (373.229 us; speedup 1.0000x reference)
//
#include <hip/hip_runtime.h>
#include <math.h>

#define IN_CH 128
#define HID 64
#define OUT_CH 10

typedef unsigned int uint32;
typedef unsigned short bf16u;

static __device__ inline bf16u f2bf(float f) {
    uint32 u = __float_as_uint(f);
    u += 0x7fff + ((u >> 16) & 1);          // round-nearest-even
    return (bf16u)(u >> 16);
}
static __device__ inline float bflo(uint32 u) {   // low bf16 of packed pair
    return __uint_as_float(u << 16);
}
static __device__ inline float bfhi(uint32 u) {   // high bf16 of packed pair
    return __uint_as_float(u & 0xffff0000u);
}

// neighbor-sum for one node: lanes (c2,h); h=0/1 halves take alternate nbrs.
// col loads via int4 broadcast (2 VMEM per 8 edges). Caller merges h-halves.
static __device__ inline void gather_nbrs(
    const uint32* __restrict__ y32, const int* __restrict__ col,
    int rs, int re, int h, int c2, float& ax, float& ay)
{
    int j = rs;
    int lead = (4 - (j & 3)) & 3;
    if (lead > re - j) lead = re - j;
    for (int q = 0; q < lead; q++) {
        if (h == 0) {
            uint32 u = y32[(long)col[j + q] * 32 + c2];
            ax += bflo(u); ay += bfhi(u);
        }
    }
    j += lead;
    for (; j + 8 <= re; j += 8) {
        int4 cA = *(const int4*)&col[j];
        int4 cB = *(const int4*)&col[j + 4];
        int sA = h ? cA.y : cA.x;
        int sB = h ? cA.w : cA.z;
        int sC = h ? cB.y : cB.x;
        int sD = h ? cB.w : cB.z;
        uint32 uA = y32[(long)sA * 32 + c2];
        uint32 uB = y32[(long)sB * 32 + c2];
        uint32 uC = y32[(long)sC * 32 + c2];
        uint32 uD = y32[(long)sD * 32 + c2];
        ax += (bflo(uA) + bflo(uB)) + (bflo(uC) + bflo(uD));
        ay += (bfhi(uA) + bfhi(uB)) + (bfhi(uC) + bfhi(uD));
    }
    if (j + 4 <= re) {
        int4 cA = *(const int4*)&col[j];
        int sA = h ? cA.y : cA.x;
        int sB = h ? cA.w : cA.z;
        uint32 uA = y32[(long)sA * 32 + c2];
        uint32 uB = y32[(long)sB * 32 + c2];
        ax += bflo(uA) + bflo(uB); ay += bfhi(uA) + bfhi(uB);
        j += 4;
    }
    if (j + 2 <= re) {
        int s = col[j + h];
        uint32 u = y32[(long)s * 32 + c2];
        ax += bflo(u); ay += bfhi(u);
        j += 2;
    }
    if (j < re && h == 0) {
        uint32 u = y32[(long)col[j] * 32 + c2];
        ax += bflo(u); ay += bfhi(u);
    }
}

// ---------- CSR build: degree count ----------
__global__ __launch_bounds__(256) void k_count(
    const int* __restrict__ dst, int* __restrict__ cnt, int E)
{
    int e = blockIdx.x * 256 + threadIdx.x;
    if (e < E) atomicAdd(&cnt[dst[e]], 1);
}

// ---------- scan stage 1 ----------
__global__ __launch_bounds__(256) void k_scan1(
    const int* __restrict__ cnt, int* __restrict__ partials, int N)
{
    __shared__ int red[256];
    int tid = threadIdx.x;
    long base = (long)blockIdx.x * 1024 + tid * 4;
    int s = 0;
    #pragma unroll
    for (int i = 0; i < 4; i++) { long idx = base + i; if (idx < N) s += cnt[idx]; }
    red[tid] = s;
    __syncthreads();
    for (int off = 128; off; off >>= 1) {
        if (tid < off) red[tid] += red[tid + off];
        __syncthreads();
    }
    if (tid == 0) partials[blockIdx.x] = red[0];
}

// ---------- scan stage 2 ----------
__global__ __launch_bounds__(64) void k_scan2(
    const int* __restrict__ partials, int* __restrict__ poff, int nch)
{
    int lane = threadIdx.x;
    int carry = 0;
    for (int base = 0; base < nch; base += 64) {
        int i = base + lane;
        int v = (i < nch) ? partials[i] : 0;
        int incl = v;
        #pragma unroll
        for (int off = 1; off < 64; off <<= 1) {
            int t = __shfl_up(incl, off);
            if (lane >= off) incl += t;
        }
        if (i < nch) poff[i] = carry + incl - v;
        carry += __shfl(incl, 63);
    }
}

// ---------- scan stage 3 ----------
__global__ __launch_bounds__(256) void k_scan3(
    const int* __restrict__ cnt, const int* __restrict__ poff,
    int* __restrict__ row_ptr, int N, int E)
{
    __shared__ int lds[256];
    int tid = threadIdx.x;
    long base = (long)blockIdx.x * 1024 + tid * 4;
    int v[4]; int s = 0;
    #pragma unroll
    for (int i = 0; i < 4; i++) {
        long idx = base + i;
        v[i] = (idx < N) ? cnt[idx] : 0;
        s += v[i];
    }
    lds[tid] = s;
    __syncthreads();
    for (int off = 1; off < 256; off <<= 1) {
        int t = (tid >= off) ? lds[tid - off] : 0;
        __syncthreads();
        lds[tid] += t;
        __syncthreads();
    }
    int run = poff[blockIdx.x] + lds[tid] - s;
    #pragma unroll
    for (int i = 0; i < 4; i++) {
        long idx = base + i;
        if (idx < N) row_ptr[idx] = run;
        run += v[i];
    }
    if (blockIdx.x == 0 && tid == 0) row_ptr[N] = E;
}

// ---------- CSR build: place edges ----------
__global__ __launch_bounds__(256) void k_place(
    const int* __restrict__ src, const int* __restrict__ dst,
    const int* __restrict__ row_ptr, int* __restrict__ fill,
    int* __restrict__ col, int E)
{
    int e = blockIdx.x * 256 + threadIdx.x;
    if (e >= E) return;
    int d = dst[e];
    int pos = atomicAdd(&fill[d], 1);
    col[row_ptr[d] + pos] = src[e];
}

// ---------- dense GEMM: y0[N,64](bf16) = x[N,128] @ w0a[128,64] ----------
// 4 waves/block, 4 nodes/wave, no main-loop barriers; bf16-packed weights.
__global__ __launch_bounds__(256) void k_lin0(
    const float2* __restrict__ x2, const float* __restrict__ w,
    bf16u* __restrict__ y, int N)
{
    __shared__ uint32 lw[(IN_CH / 2) * HID];  // 16 KB, [k2][c] packed (k,k+1)
    __shared__ float t[16][IN_CH];            // 8 KB, per-wave rows
    int tid = threadIdx.x;
    for (int i = tid; i < (IN_CH / 2) * HID; i += 256) {
        int k2 = i >> 6, c = i & 63;
        float f0 = w[(2 * k2) * HID + c];
        float f1 = w[(2 * k2 + 1) * HID + c];
        lw[i] = (uint32)f2bf(f0) | ((uint32)f2bf(f1) << 16);
    }
    int wid = tid >> 6, c = tid & 63;
    int n0 = wid * 4;
    __syncthreads();
    for (long g0 = (long)blockIdx.x * 16; g0 < N; g0 += (long)gridDim.x * 16) {
        #pragma unroll
        for (int m = 0; m < 4; m++) {
            long node = g0 + n0 + m;
            if (node < N)
                *(float2*)&t[n0 + m][2 * c] = x2[node * 64 + c];
        }
        float a0 = 0.f, a1 = 0.f, a2 = 0.f, a3 = 0.f;
        #pragma unroll 8
        for (int k4 = 0; k4 < IN_CH / 4; k4++) {
            float4 t0 = *(const float4*)&t[n0 + 0][k4 * 4];
            float4 t1 = *(const float4*)&t[n0 + 1][k4 * 4];
            float4 t2 = *(const float4*)&t[n0 + 2][k4 * 4];
            float4 t3 = *(const float4*)&t[n0 + 3][k4 * 4];
            uint32 u01 = lw[(k4 * 2 + 0) * HID + c];
            uint32 u23 = lw[(k4 * 2 + 1) * HID + c];
            float w0 = bflo(u01), w1 = bfhi(u01);
            float w2 = bflo(u23), w3 = bfhi(u23);
            a0 = fmaf(t0.w, w3, fmaf(t0.z, w2, fmaf(t0.y, w1, fmaf(t0.x, w0, a0))));
            a1 = fmaf(t1.w, w3, fmaf(t1.z, w2, fmaf(t1.y, w1, fmaf(t1.x, w0, a1))));
            a2 = fmaf(t2.w, w3, fmaf(t2.z, w2, fmaf(t2.y, w1, fmaf(t2.x, w0, a2))));
            a3 = fmaf(t3.w, w3, fmaf(t3.z, w2, fmaf(t3.y, w1, fmaf(t3.x, w0, a3))));
        }
        float accv[4] = {a0, a1, a2, a3};
        #pragma unroll
        for (int m = 0; m < 4; m++) {
            long node = g0 + n0 + m;
            if (node < N) y[node * HID + c] = f2bf(accv[m]);
        }
    }
}

// ---------- layer-0 gather + MLP-b + fused lin1 ----------
// y1 = ( relu( relu((1+e)y0 + sum y0[nbr] + b0a) @ w0b + b0b ) ) @ w1a
__global__ __launch_bounds__(256) void k_agg0f(
    const uint32* __restrict__ y32, const int* __restrict__ row_ptr,
    const int* __restrict__ col, const float* __restrict__ epsp,
    const float* __restrict__ ba, const float* __restrict__ wb,
    const float* __restrict__ bb, const float* __restrict__ w1a,
    bf16u* __restrict__ y1, int N)
{
    __shared__ uint32 lwb[(HID / 2) * HID];   // 8 KB packed
    __shared__ uint32 lw1[(HID / 2) * HID];   // 8 KB packed
    __shared__ float t[16][HID];              // 4 KB
    __shared__ float h2[16][HID];             // 4 KB
    int tid = threadIdx.x;
    for (int i = tid; i < (HID / 2) * HID; i += 256) {
        int k2 = i >> 6, c = i & 63;
        lwb[i] = (uint32)f2bf(wb[(2 * k2) * HID + c]) |
                 ((uint32)f2bf(wb[(2 * k2 + 1) * HID + c]) << 16);
        lw1[i] = (uint32)f2bf(w1a[(2 * k2) * HID + c]) |
                 ((uint32)f2bf(w1a[(2 * k2 + 1) * HID + c]) << 16);
    }
    float e = 1.f + epsp[0];
    int wid = tid >> 6, lane = tid & 63;
    int c2 = lane & 31, h = lane >> 5;
    int c = lane;
    int n0 = wid * 4;
    float2 bav = ((const float2*)ba)[c2];
    float bbv = bb[c];
    __syncthreads();
    for (long g0 = (long)blockIdx.x * 16; g0 < N; g0 += (long)gridDim.x * 16) {
        for (int m = 0; m < 4; m++) {
            long node = g0 + n0 + m;
            float ax = 0.f, ay = 0.f;
            if (node < N) {
                int rs = row_ptr[node], re = row_ptr[node + 1];
                gather_nbrs(y32, col, rs, re, h, c2, ax, ay);
                if (h == 0) {
                    uint32 u = y32[node * 32 + c2];
                    ax = fmaf(e, bflo(u), ax); ay = fmaf(e, bfhi(u), ay);
                }
            }
            ax += __shfl_xor(ax, 32);
            ay += __shfl_xor(ay, 32);
            if (h == 0) {
                float2 v;
                v.x = fmaxf(ax + bav.x, 0.f);
                v.y = fmaxf(ay + bav.y, 0.f);
                *(float2*)&t[n0 + m][2 * c2] = v;
            }
        }
        // ---- M1: h2 = relu(t @ wb + bb)
        {
            float a0 = bbv, a1 = bbv, a2 = bbv, a3 = bbv;
            #pragma unroll 8
            for (int k4 = 0; k4 < HID / 4; k4++) {
                float4 t0 = *(const float4*)&t[n0 + 0][k4 * 4];
                float4 t1 = *(const float4*)&t[n0 + 1][k4 * 4];
                float4 t2 = *(const float4*)&t[n0 + 2][k4 * 4];
                float4 t3 = *(const float4*)&t[n0 + 3][k4 * 4];
                uint32 u01 = lwb[(k4 * 2 + 0) * HID + c];
                uint32 u23 = lwb[(k4 * 2 + 1) * HID + c];
                float w0 = bflo(u01), w1 = bfhi(u01);
                float w2 = bflo(u23), w3 = bfhi(u23);
                a0 = fmaf(t0.w, w3, fmaf(t0.z, w2, fmaf(t0.y, w1, fmaf(t0.x, w0, a0))));
                a1 = fmaf(t1.w, w3, fmaf(t1.z, w2, fmaf(t1.y, w1, fmaf(t1.x, w0, a1))));
                a2 = fmaf(t2.w, w3, fmaf(t2.z, w2, fmaf(t2.y, w1, fmaf(t2.x, w0, a2))));
                a3 = fmaf(t3.w, w3, fmaf(t3.z, w2, fmaf(t3.y, w1, fmaf(t3.x, w0, a3))));
            }
            h2[n0 + 0][c] = fmaxf(a0, 0.f);
            h2[n0 + 1][c] = fmaxf(a1, 0.f);
            h2[n0 + 2][c] = fmaxf(a2, 0.f);
            h2[n0 + 3][c] = fmaxf(a3, 0.f);
        }
        // ---- M2: y1 = h2 @ w1a
        {
            float a0 = 0.f, a1 = 0.f, a2 = 0.f, a3 = 0.f;
            #pragma unroll 8
            for (int k4 = 0; k4 < HID / 4; k4++) {
                float4 t0 = *(const float4*)&h2[n0 + 0][k4 * 4];
                float4 t1 = *(const float4*)&h2[n0 + 1][k4 * 4];
                float4 t2 = *(const float4*)&h2[n0 + 2][k4 * 4];
                float4 t3 = *(const float4*)&h2[n0 + 3][k4 * 4];
                uint32 u01 = lw1[(k4 * 2 + 0) * HID + c];
                uint32 u23 = lw1[(k4 * 2 + 1) * HID + c];
                float w0 = bflo(u01), w1 = bfhi(u01);
                float w2 = bflo(u23), w3 = bfhi(u23);
                a0 = fmaf(t0.w, w3, fmaf(t0.z, w2, fmaf(t0.y, w1, fmaf(t0.x, w0, a0))));
                a1 = fmaf(t1.w, w3, fmaf(t1.z, w2, fmaf(t1.y, w1, fmaf(t1.x, w0, a1))));
                a2 = fmaf(t2.w, w3, fmaf(t2.z, w2, fmaf(t2.y, w1, fmaf(t2.x, w0, a2))));
                a3 = fmaf(t3.w, w3, fmaf(t3.z, w2, fmaf(t3.y, w1, fmaf(t3.x, w0, a3))));
            }
            float accv[4] = {a0, a1, a2, a3};
            #pragma unroll
            for (int m = 0; m < 4; m++) {
                long node = g0 + n0 + m;
                if (node < N) y1[node * HID + c] = f2bf(accv[m]);
            }
        }
    }
}

// ---------- layer-1 gather + MLP-b + pooling ----------
__global__ __launch_bounds__(256) void k_agg1(
    const uint32* __restrict__ y32, const int* __restrict__ row_ptr,
    const int* __restrict__ col, const float* __restrict__ epsp,
    const float* __restrict__ ba, const float* __restrict__ wb,
    const float* __restrict__ bb, const int* __restrict__ batch,
    float* __restrict__ pooled, int N)
{
    __shared__ uint32 lwb[(HID / 2) * HID];   // 8 KB packed
    __shared__ float t[16][HID];              // 4 KB
    int tid = threadIdx.x;
    for (int i = tid; i < (HID / 2) * HID; i += 256) {
        int k2 = i >> 6, c = i & 63;
        lwb[i] = (uint32)f2bf(wb[(2 * k2) * HID + c]) |
                 ((uint32)f2bf(wb[(2 * k2 + 1) * HID + c]) << 16);
    }
    float e = 1.f + epsp[0];
    int wid = tid >> 6, lane = tid & 63;
    int c2 = lane & 31, h = lane >> 5;
    int c = lane;
    int n0 = wid * 4;
    float2 bav = ((const float2*)ba)[c2];
    float bbv = bb[c];
    __syncthreads();
    for (long g0 = (long)blockIdx.x * 16; g0 < N; g0 += (long)gridDim.x * 16) {
        for (int m = 0; m < 4; m++) {
            long node = g0 + n0 + m;
            float ax = 0.f, ay = 0.f;
            if (node < N) {
                int rs = row_ptr[node], re = row_ptr[node + 1];
                gather_nbrs(y32, col, rs, re, h, c2, ax, ay);
                if (h == 0) {
                    uint32 u = y32[node * 32 + c2];
                    ax = fmaf(e, bflo(u), ax); ay = fmaf(e, bfhi(u), ay);
                }
            }
            ax += __shfl_xor(ax, 32);
            ay += __shfl_xor(ay, 32);
            if (h == 0) {
                float2 v;
                v.x = fmaxf(ax + bav.x, 0.f);
                v.y = fmaxf(ay + bav.y, 0.f);
                *(float2*)&t[n0 + m][2 * c2] = v;
            }
        }
        // M1: r = relu(t @ w1b + b1b), then pooled[batch] += r
        float a0 = bbv, a1 = bbv, a2 = bbv, a3 = bbv;
        #pragma unroll 8
        for (int k4 = 0; k4 < HID / 4; k4++) {
            float4 t0 = *(const float4*)&t[n0 + 0][k4 * 4];
            float4 t1 = *(const float4*)&t[n0 + 1][k4 * 4];
            float4 t2 = *(const float4*)&t[n0 + 2][k4 * 4];
            float4 t3 = *(const float4*)&t[n0 + 3][k4 * 4];
            uint32 u01 = lwb[(k4 * 2 + 0) * HID + c];
            uint32 u23 = lwb[(k4 * 2 + 1) * HID + c];
            float w0 = bflo(u01), w1 = bfhi(u01);
            float w2 = bflo(u23), w3 = bfhi(u23);
            a0 = fmaf(t0.w, w3, fmaf(t0.z, w2, fmaf(t0.y, w1, fmaf(t0.x, w0, a0))));
            a1 = fmaf(t1.w, w3, fmaf(t1.z, w2, fmaf(t1.y, w1, fmaf(t1.x, w0, a1))));
            a2 = fmaf(t2.w, w3, fmaf(t2.z, w2, fmaf(t2.y, w1, fmaf(t2.x, w0, a2))));
            a3 = fmaf(t3.w, w3, fmaf(t3.z, w2, fmaf(t3.y, w1, fmaf(t3.x, w0, a3))));
        }
        float accv[4] = {fmaxf(a0, 0.f), fmaxf(a1, 0.f), fmaxf(a2, 0.f), fmaxf(a3, 0.f)};
        long nodeA = g0 + n0;
        int nv = (int)((N - nodeA) < 4 ? (N - nodeA) : 4);
        if (nv > 0) {
            int bf = batch[nodeA], bl = batch[nodeA + nv - 1];
            if (bf == bl) {
                float s = 0.f;
                for (int n = 0; n < nv; n++) s += accv[n];
                atomicAdd(&pooled[(long)bf * HID + c], s);
            } else {
                for (int n = 0; n < nv; n++)
                    atomicAdd(&pooled[(long)batch[nodeA + n] * HID + c], accv[n]);
            }
        }
    }
}

// ---------- head: logits = pooled@fcw+fcb; log_softmax ----------
__global__ __launch_bounds__(64) void k_head(
    const float* __restrict__ pooled, const float* __restrict__ fcw,
    const float* __restrict__ fcb, float* __restrict__ out)
{
    int g = blockIdx.x;
    int l = threadIdx.x;
    float logit = -INFINITY;
    if (l < OUT_CH) {
        float acc = fcb[l];
        #pragma unroll
        for (int k = 0; k < HID; k++)
            acc = fmaf(pooled[g * HID + k], fcw[k * OUT_CH + l], acc);
        logit = acc;
    }
    float m = logit;
    #pragma unroll
    for (int off = 32; off; off >>= 1) m = fmaxf(m, __shfl_xor(m, off));
    float ex = (l < OUT_CH) ? expf(logit - m) : 0.0f;
    float s = ex;
    #pragma unroll
    for (int off = 32; off; off >>= 1) s += __shfl_xor(s, off);
    if (l < OUT_CH) out[g * OUT_CH + l] = logit - m - logf(s);
}

extern "C" void kernel_launch(void* const* d_in, const int* in_sizes, int n_in,
                              void* d_out, int out_size, void* d_ws, size_t ws_size,
                              hipStream_t stream) {
    const float* x    = (const float*)d_in[0];
    const int*   ei   = (const int*)d_in[1];
    const int*   batch= (const int*)d_in[2];
    const float* eps0 = (const float*)d_in[3];
    const float* w0a  = (const float*)d_in[4];
    const float* b0a  = (const float*)d_in[5];
    const float* w0b  = (const float*)d_in[6];
    const float* b0b  = (const float*)d_in[7];
    const float* eps1 = (const float*)d_in[8];
    const float* w1a  = (const float*)d_in[9];
    const float* b1a  = (const float*)d_in[10];
    const float* w1b  = (const float*)d_in[11];
    const float* b1b  = (const float*)d_in[12];
    const float* fcw  = (const float*)d_in[13];
    const float* fcb  = (const float*)d_in[14];
    float* out = (float*)d_out;

    const int N = in_sizes[0] / IN_CH;       // 50000
    const int E = in_sizes[1] / 2;           // 800000
    const int G = out_size / OUT_CH;         // 512
    const int* src = ei;
    const int* dst = ei + E;

    // workspace layout (bytes):
    // [0, 200064)             row_ptr  (N+1 ints)
    // [200064, 3400064)       col      (E ints)   (16B-aligned base)
    // [3400064, 9800064)      y0       (N*64 bf16)
    // [9800064, 16200064)     y1       (N*64 bf16)
    //    cnt      @ 9800064   (N ints)      -- overlay, dead before y1 written
    //    fill     @ 10000128  (N ints)
    //    partials @ 10200192  (256 B)
    //    poff     @ 10200448  (256 B)
    // [16200064, 16331136)    pooled   (G*64 fp32)
    char* ws = (char*)d_ws;
    int*    row_ptr  = (int*)(ws);
    int*    colv     = (int*)(ws + 200064);
    bf16u*  y0       = (bf16u*)(ws + 3400064);
    bf16u*  y1       = (bf16u*)(ws + 9800064);
    int*    cnt      = (int*)(ws + 9800064);
    int*    fill     = (int*)(ws + 10000128);
    int*    partials = (int*)(ws + 10200192);
    int*    poff     = (int*)(ws + 10200448);
    float*  pooled   = (float*)(ws + 16200064);

    hipMemsetAsync(cnt, 0, 400128, stream);     // covers cnt + fill
    hipMemsetAsync(pooled, 0, (size_t)G * HID * sizeof(float), stream);

    int eb = (E + 255) / 256;
    int nch = (N + 1023) / 1024;                // scan chunks (49)
    k_count<<<eb, 256, 0, stream>>>(dst, cnt, E);
    k_scan1<<<nch, 256, 0, stream>>>(cnt, partials, N);
    k_scan2<<<1, 64, 0, stream>>>(partials, poff, nch);
    k_scan3<<<nch, 256, 0, stream>>>(cnt, poff, row_ptr, N, E);
    k_place<<<eb, 256, 0, stream>>>(src, dst, row_ptr, fill, colv, E);

    int nb = (N + 15) / 16;                     // 3125
    k_lin0<<<nb, 256, 0, stream>>>((const float2*)x, w0a, y0, N);
    k_agg0f<<<nb, 256, 0, stream>>>((const uint32*)y0, row_ptr, colv, eps0,
                                    b0a, w0b, b0b, w1a, y1, N);
    k_agg1<<<nb, 256, 0, stream>>>((const uint32*)y1, row_ptr, colv, eps1,
                                   b1a, w1b, b1b, batch, pooled, N);
    k_head<<<G, 64, 0, stream>>>(pooled, fcw, fcb, out);
}

// Round 8
// 319.585 us; speedup vs baseline: 1.1679x; 1.1679x over previous
//
#include <hip/hip_runtime.h>
#include <math.h>

#define IN_CH 128
#define HID 64
#define OUT_CH 10

typedef unsigned int uint32;
typedef unsigned short bf16u;

static __device__ inline bf16u f2bf(float f) {
    uint32 u = __float_as_uint(f);
    u += 0x7fff + ((u >> 16) & 1);          // round-nearest-even
    return (bf16u)(u >> 16);
}
static __device__ inline float bflo(uint32 u) {   // low bf16 of packed pair
    return __uint_as_float(u << 16);
}
static __device__ inline float bfhi(uint32 u) {   // high bf16 of packed pair
    return __uint_as_float(u & 0xffff0000u);
}

// neighbor-sum for one node: lanes (c2,h); h=0/1 halves take alternate nbrs.
// R6-proven form: scalar col loads (wave sees only 2 distinct dwords -> 1 VMEM).
static __device__ inline void gather_nbrs(
    const uint32* __restrict__ y32, const int* __restrict__ col,
    int rs, int re, int h, int c2, float& ax, float& ay)
{
    int j = rs;
    for (; j + 8 <= re; j += 8) {
        int sA = col[j + h],     sB = col[j + 2 + h];
        int sC = col[j + 4 + h], sD = col[j + 6 + h];
        uint32 uA = y32[(long)sA * 32 + c2];
        uint32 uB = y32[(long)sB * 32 + c2];
        uint32 uC = y32[(long)sC * 32 + c2];
        uint32 uD = y32[(long)sD * 32 + c2];
        ax += (bflo(uA) + bflo(uB)) + (bflo(uC) + bflo(uD));
        ay += (bfhi(uA) + bfhi(uB)) + (bfhi(uC) + bfhi(uD));
    }
    for (; j + 2 <= re; j += 2) {
        int s = col[j + h];
        uint32 u = y32[(long)s * 32 + c2];
        ax += bflo(u); ay += bfhi(u);
    }
    if (j < re && h == 0) {
        uint32 u = y32[(long)col[j] * 32 + c2];
        ax += bflo(u); ay += bfhi(u);
    }
}

// ---------- CSR build: degree count ----------
__global__ __launch_bounds__(256) void k_count(
    const int* __restrict__ dst, int* __restrict__ cnt, int E)
{
    int e = blockIdx.x * 256 + threadIdx.x;
    if (e < E) atomicAdd(&cnt[dst[e]], 1);
}

// ---------- scan stage 1 ----------
__global__ __launch_bounds__(256) void k_scan1(
    const int* __restrict__ cnt, int* __restrict__ partials, int N)
{
    __shared__ int red[256];
    int tid = threadIdx.x;
    long base = (long)blockIdx.x * 1024 + tid * 4;
    int s = 0;
    #pragma unroll
    for (int i = 0; i < 4; i++) { long idx = base + i; if (idx < N) s += cnt[idx]; }
    red[tid] = s;
    __syncthreads();
    for (int off = 128; off; off >>= 1) {
        if (tid < off) red[tid] += red[tid + off];
        __syncthreads();
    }
    if (tid == 0) partials[blockIdx.x] = red[0];
}

// ---------- scan stage 2 ----------
__global__ __launch_bounds__(64) void k_scan2(
    const int* __restrict__ partials, int* __restrict__ poff, int nch)
{
    int lane = threadIdx.x;
    int carry = 0;
    for (int base = 0; base < nch; base += 64) {
        int i = base + lane;
        int v = (i < nch) ? partials[i] : 0;
        int incl = v;
        #pragma unroll
        for (int off = 1; off < 64; off <<= 1) {
            int t = __shfl_up(incl, off);
            if (lane >= off) incl += t;
        }
        if (i < nch) poff[i] = carry + incl - v;
        carry += __shfl(incl, 63);
    }
}

// ---------- scan stage 3 ----------
__global__ __launch_bounds__(256) void k_scan3(
    const int* __restrict__ cnt, const int* __restrict__ poff,
    int* __restrict__ row_ptr, int N, int E)
{
    __shared__ int lds[256];
    int tid = threadIdx.x;
    long base = (long)blockIdx.x * 1024 + tid * 4;
    int v[4]; int s = 0;
    #pragma unroll
    for (int i = 0; i < 4; i++) {
        long idx = base + i;
        v[i] = (idx < N) ? cnt[idx] : 0;
        s += v[i];
    }
    lds[tid] = s;
    __syncthreads();
    for (int off = 1; off < 256; off <<= 1) {
        int t = (tid >= off) ? lds[tid - off] : 0;
        __syncthreads();
        lds[tid] += t;
        __syncthreads();
    }
    int run = poff[blockIdx.x] + lds[tid] - s;
    #pragma unroll
    for (int i = 0; i < 4; i++) {
        long idx = base + i;
        if (idx < N) row_ptr[idx] = run;
        run += v[i];
    }
    if (blockIdx.x == 0 && tid == 0) row_ptr[N] = E;
}

// ---------- CSR build: place edges ----------
__global__ __launch_bounds__(256) void k_place(
    const int* __restrict__ src, const int* __restrict__ dst,
    const int* __restrict__ row_ptr, int* __restrict__ fill,
    int* __restrict__ col, int E)
{
    int e = blockIdx.x * 256 + threadIdx.x;
    if (e >= E) return;
    int d = dst[e];
    int pos = atomicAdd(&fill[d], 1);
    col[row_ptr[d] + pos] = src[e];
}

// ---------- dense GEMM: y0[N,64](bf16) = x[N,128] @ w0a[128,64] ----------
__global__ __launch_bounds__(256) void k_lin0(
    const float2* __restrict__ x2, const float* __restrict__ w,
    bf16u* __restrict__ y, int N)
{
    __shared__ uint32 lw[(IN_CH / 2) * HID];  // 16 KB packed
    __shared__ float t[16][IN_CH];            // 8 KB, per-wave rows
    int tid = threadIdx.x;
    for (int i = tid; i < (IN_CH / 2) * HID; i += 256) {
        int k2 = i >> 6, c = i & 63;
        lw[i] = (uint32)f2bf(w[(2 * k2) * HID + c]) |
                ((uint32)f2bf(w[(2 * k2 + 1) * HID + c]) << 16);
    }
    int wid = tid >> 6, c = tid & 63;
    int n0 = wid * 4;
    __syncthreads();
    for (long g0 = (long)blockIdx.x * 16; g0 < N; g0 += (long)gridDim.x * 16) {
        #pragma unroll
        for (int m = 0; m < 4; m++) {
            long node = g0 + n0 + m;
            if (node < N)
                *(float2*)&t[n0 + m][2 * c] = x2[node * 64 + c];
        }
        float a0 = 0.f, a1 = 0.f, a2 = 0.f, a3 = 0.f;
        #pragma unroll 8
        for (int k4 = 0; k4 < IN_CH / 4; k4++) {
            float4 t0 = *(const float4*)&t[n0 + 0][k4 * 4];
            float4 t1 = *(const float4*)&t[n0 + 1][k4 * 4];
            float4 t2 = *(const float4*)&t[n0 + 2][k4 * 4];
            float4 t3 = *(const float4*)&t[n0 + 3][k4 * 4];
            uint32 u01 = lw[(k4 * 2 + 0) * HID + c];
            uint32 u23 = lw[(k4 * 2 + 1) * HID + c];
            float w0 = bflo(u01), w1 = bfhi(u01);
            float w2 = bflo(u23), w3 = bfhi(u23);
            a0 = fmaf(t0.w, w3, fmaf(t0.z, w2, fmaf(t0.y, w1, fmaf(t0.x, w0, a0))));
            a1 = fmaf(t1.w, w3, fmaf(t1.z, w2, fmaf(t1.y, w1, fmaf(t1.x, w0, a1))));
            a2 = fmaf(t2.w, w3, fmaf(t2.z, w2, fmaf(t2.y, w1, fmaf(t2.x, w0, a2))));
            a3 = fmaf(t3.w, w3, fmaf(t3.z, w2, fmaf(t3.y, w1, fmaf(t3.x, w0, a3))));
        }
        float accv[4] = {a0, a1, a2, a3};
        #pragma unroll
        for (int m = 0; m < 4; m++) {
            long node = g0 + n0 + m;
            if (node < N) y[node * HID + c] = f2bf(accv[m]);
        }
    }
}

// ---------- layer-0 gather + MLP-b + fused lin1 ----------
// y1 = ( relu( relu((1+e)y0 + sum y0[nbr] + b0a) @ w0b + b0b ) ) @ w1a
// t is reused for h2 (wave-private rows; M1 reads complete before overwrite).
__global__ __launch_bounds__(256, 8) void k_agg0f(
    const uint32* __restrict__ y32, const int* __restrict__ row_ptr,
    const int* __restrict__ col, const float* __restrict__ epsp,
    const float* __restrict__ ba, const float* __restrict__ wb,
    const float* __restrict__ bb, const float* __restrict__ w1a,
    bf16u* __restrict__ y1, int N)
{
    __shared__ uint32 lwb[(HID / 2) * HID];   // 8 KB packed
    __shared__ uint32 lw1[(HID / 2) * HID];   // 8 KB packed
    __shared__ float t[16][HID];              // 4 KB (t, then reused as h2)
    int tid = threadIdx.x;
    for (int i = tid; i < (HID / 2) * HID; i += 256) {
        int k2 = i >> 6, c = i & 63;
        lwb[i] = (uint32)f2bf(wb[(2 * k2) * HID + c]) |
                 ((uint32)f2bf(wb[(2 * k2 + 1) * HID + c]) << 16);
        lw1[i] = (uint32)f2bf(w1a[(2 * k2) * HID + c]) |
                 ((uint32)f2bf(w1a[(2 * k2 + 1) * HID + c]) << 16);
    }
    float e = 1.f + epsp[0];
    int wid = tid >> 6, lane = tid & 63;
    int c2 = lane & 31, h = lane >> 5;
    int c = lane;
    int n0 = wid * 4;
    float2 bav = ((const float2*)ba)[c2];
    float bbv = bb[c];
    __syncthreads();
    for (long g0 = (long)blockIdx.x * 16; g0 < N; g0 += (long)gridDim.x * 16) {
        for (int m = 0; m < 4; m++) {
            long node = g0 + n0 + m;
            float ax = 0.f, ay = 0.f;
            if (node < N) {
                int rs = row_ptr[node], re = row_ptr[node + 1];
                gather_nbrs(y32, col, rs, re, h, c2, ax, ay);
                if (h == 0) {
                    uint32 u = y32[node * 32 + c2];
                    ax = fmaf(e, bflo(u), ax); ay = fmaf(e, bfhi(u), ay);
                }
            }
            ax += __shfl_xor(ax, 32);
            ay += __shfl_xor(ay, 32);
            if (h == 0) {
                float2 v;
                v.x = fmaxf(ax + bav.x, 0.f);
                v.y = fmaxf(ay + bav.y, 0.f);
                *(float2*)&t[n0 + m][2 * c2] = v;
            }
        }
        // ---- M1: h2 = relu(t @ wb + bb); write back into t (wave-private)
        {
            float a0 = bbv, a1 = bbv, a2 = bbv, a3 = bbv;
            #pragma unroll 8
            for (int k4 = 0; k4 < HID / 4; k4++) {
                float4 t0 = *(const float4*)&t[n0 + 0][k4 * 4];
                float4 t1 = *(const float4*)&t[n0 + 1][k4 * 4];
                float4 t2 = *(const float4*)&t[n0 + 2][k4 * 4];
                float4 t3 = *(const float4*)&t[n0 + 3][k4 * 4];
                uint32 u01 = lwb[(k4 * 2 + 0) * HID + c];
                uint32 u23 = lwb[(k4 * 2 + 1) * HID + c];
                float w0 = bflo(u01), w1 = bfhi(u01);
                float w2 = bflo(u23), w3 = bfhi(u23);
                a0 = fmaf(t0.w, w3, fmaf(t0.z, w2, fmaf(t0.y, w1, fmaf(t0.x, w0, a0))));
                a1 = fmaf(t1.w, w3, fmaf(t1.z, w2, fmaf(t1.y, w1, fmaf(t1.x, w0, a1))));
                a2 = fmaf(t2.w, w3, fmaf(t2.z, w2, fmaf(t2.y, w1, fmaf(t2.x, w0, a2))));
                a3 = fmaf(t3.w, w3, fmaf(t3.z, w2, fmaf(t3.y, w1, fmaf(t3.x, w0, a3))));
            }
            t[n0 + 0][c] = fmaxf(a0, 0.f);
            t[n0 + 1][c] = fmaxf(a1, 0.f);
            t[n0 + 2][c] = fmaxf(a2, 0.f);
            t[n0 + 3][c] = fmaxf(a3, 0.f);
        }
        // ---- M2: y1 = h2 @ w1a
        {
            float a0 = 0.f, a1 = 0.f, a2 = 0.f, a3 = 0.f;
            #pragma unroll 8
            for (int k4 = 0; k4 < HID / 4; k4++) {
                float4 t0 = *(const float4*)&t[n0 + 0][k4 * 4];
                float4 t1 = *(const float4*)&t[n0 + 1][k4 * 4];
                float4 t2 = *(const float4*)&t[n0 + 2][k4 * 4];
                float4 t3 = *(const float4*)&t[n0 + 3][k4 * 4];
                uint32 u01 = lw1[(k4 * 2 + 0) * HID + c];
                uint32 u23 = lw1[(k4 * 2 + 1) * HID + c];
                float w0 = bflo(u01), w1 = bfhi(u01);
                float w2 = bflo(u23), w3 = bfhi(u23);
                a0 = fmaf(t0.w, w3, fmaf(t0.z, w2, fmaf(t0.y, w1, fmaf(t0.x, w0, a0))));
                a1 = fmaf(t1.w, w3, fmaf(t1.z, w2, fmaf(t1.y, w1, fmaf(t1.x, w0, a1))));
                a2 = fmaf(t2.w, w3, fmaf(t2.z, w2, fmaf(t2.y, w1, fmaf(t2.x, w0, a2))));
                a3 = fmaf(t3.w, w3, fmaf(t3.z, w2, fmaf(t3.y, w1, fmaf(t3.x, w0, a3))));
            }
            float accv[4] = {a0, a1, a2, a3};
            #pragma unroll
            for (int m = 0; m < 4; m++) {
                long node = g0 + n0 + m;
                if (node < N) y1[node * HID + c] = f2bf(accv[m]);
            }
        }
    }
}

// ---------- layer-1 gather + MLP-b + pooling ----------
__global__ __launch_bounds__(256, 8) void k_agg1(
    const uint32* __restrict__ y32, const int* __restrict__ row_ptr,
    const int* __restrict__ col, const float* __restrict__ epsp,
    const float* __restrict__ ba, const float* __restrict__ wb,
    const float* __restrict__ bb, const int* __restrict__ batch,
    float* __restrict__ pooled, int N)
{
    __shared__ uint32 lwb[(HID / 2) * HID];   // 8 KB packed
    __shared__ float t[16][HID];              // 4 KB
    int tid = threadIdx.x;
    for (int i = tid; i < (HID / 2) * HID; i += 256) {
        int k2 = i >> 6, c = i & 63;
        lwb[i] = (uint32)f2bf(wb[(2 * k2) * HID + c]) |
                 ((uint32)f2bf(wb[(2 * k2 + 1) * HID + c]) << 16);
    }
    float e = 1.f + epsp[0];
    int wid = tid >> 6, lane = tid & 63;
    int c2 = lane & 31, h = lane >> 5;
    int c = lane;
    int n0 = wid * 4;
    float2 bav = ((const float2*)ba)[c2];
    float bbv = bb[c];
    __syncthreads();
    for (long g0 = (long)blockIdx.x * 16; g0 < N; g0 += (long)gridDim.x * 16) {
        for (int m = 0; m < 4; m++) {
            long node = g0 + n0 + m;
            float ax = 0.f, ay = 0.f;
            if (node < N) {
                int rs = row_ptr[node], re = row_ptr[node + 1];
                gather_nbrs(y32, col, rs, re, h, c2, ax, ay);
                if (h == 0) {
                    uint32 u = y32[node * 32 + c2];
                    ax = fmaf(e, bflo(u), ax); ay = fmaf(e, bfhi(u), ay);
                }
            }
            ax += __shfl_xor(ax, 32);
            ay += __shfl_xor(ay, 32);
            if (h == 0) {
                float2 v;
                v.x = fmaxf(ax + bav.x, 0.f);
                v.y = fmaxf(ay + bav.y, 0.f);
                *(float2*)&t[n0 + m][2 * c2] = v;
            }
        }
        // M1: r = relu(t @ w1b + b1b), then pooled[batch] += r
        float a0 = bbv, a1 = bbv, a2 = bbv, a3 = bbv;
        #pragma unroll 8
        for (int k4 = 0; k4 < HID / 4; k4++) {
            float4 t0 = *(const float4*)&t[n0 + 0][k4 * 4];
            float4 t1 = *(const float4*)&t[n0 + 1][k4 * 4];
            float4 t2 = *(const float4*)&t[n0 + 2][k4 * 4];
            float4 t3 = *(const float4*)&t[n0 + 3][k4 * 4];
            uint32 u01 = lwb[(k4 * 2 + 0) * HID + c];
            uint32 u23 = lwb[(k4 * 2 + 1) * HID + c];
            float w0 = bflo(u01), w1 = bfhi(u01);
            float w2 = bflo(u23), w3 = bfhi(u23);
            a0 = fmaf(t0.w, w3, fmaf(t0.z, w2, fmaf(t0.y, w1, fmaf(t0.x, w0, a0))));
            a1 = fmaf(t1.w, w3, fmaf(t1.z, w2, fmaf(t1.y, w1, fmaf(t1.x, w0, a1))));
            a2 = fmaf(t2.w, w3, fmaf(t2.z, w2, fmaf(t2.y, w1, fmaf(t2.x, w0, a2))));
            a3 = fmaf(t3.w, w3, fmaf(t3.z, w2, fmaf(t3.y, w1, fmaf(t3.x, w0, a3))));
        }
        float accv[4] = {fmaxf(a0, 0.f), fmaxf(a1, 0.f), fmaxf(a2, 0.f), fmaxf(a3, 0.f)};
        long nodeA = g0 + n0;
        int nv = (int)((N - nodeA) < 4 ? (N - nodeA) : 4);
        if (nv > 0) {
            int bf = batch[nodeA], bl = batch[nodeA + nv - 1];
            if (bf == bl) {
                float s = 0.f;
                for (int n = 0; n < nv; n++) s += accv[n];
                atomicAdd(&pooled[(long)bf * HID + c], s);
            } else {
                for (int n = 0; n < nv; n++)
                    atomicAdd(&pooled[(long)batch[nodeA + n] * HID + c], accv[n]);
            }
        }
    }
}

// ---------- head: logits = pooled@fcw+fcb; log_softmax ----------
__global__ __launch_bounds__(64) void k_head(
    const float* __restrict__ pooled, const float* __restrict__ fcw,
    const float* __restrict__ fcb, float* __restrict__ out)
{
    int g = blockIdx.x;
    int l = threadIdx.x;
    float logit = -INFINITY;
    if (l < OUT_CH) {
        float acc = fcb[l];
        #pragma unroll
        for (int k = 0; k < HID; k++)
            acc = fmaf(pooled[g * HID + k], fcw[k * OUT_CH + l], acc);
        logit = acc;
    }
    float m = logit;
    #pragma unroll
    for (int off = 32; off; off >>= 1) m = fmaxf(m, __shfl_xor(m, off));
    float ex = (l < OUT_CH) ? expf(logit - m) : 0.0f;
    float s = ex;
    #pragma unroll
    for (int off = 32; off; off >>= 1) s += __shfl_xor(s, off);
    if (l < OUT_CH) out[g * OUT_CH + l] = logit - m - logf(s);
}

extern "C" void kernel_launch(void* const* d_in, const int* in_sizes, int n_in,
                              void* d_out, int out_size, void* d_ws, size_t ws_size,
                              hipStream_t stream) {
    const float* x    = (const float*)d_in[0];
    const int*   ei   = (const int*)d_in[1];
    const int*   batch= (const int*)d_in[2];
    const float* eps0 = (const float*)d_in[3];
    const float* w0a  = (const float*)d_in[4];
    const float* b0a  = (const float*)d_in[5];
    const float* w0b  = (const float*)d_in[6];
    const float* b0b  = (const float*)d_in[7];
    const float* eps1 = (const float*)d_in[8];
    const float* w1a  = (const float*)d_in[9];
    const float* b1a  = (const float*)d_in[10];
    const float* w1b  = (const float*)d_in[11];
    const float* b1b  = (const float*)d_in[12];
    const float* fcw  = (const float*)d_in[13];
    const float* fcb  = (const float*)d_in[14];
    float* out = (float*)d_out;

    const int N = in_sizes[0] / IN_CH;       // 50000
    const int E = in_sizes[1] / 2;           // 800000
    const int G = out_size / OUT_CH;         // 512
    const int* src = ei;
    const int* dst = ei + E;

    // workspace layout (bytes):
    // [0, 200064)             row_ptr  (N+1 ints)
    // [200064, 3400064)       col      (E ints)
    // [3400064, 9800064)      y0       (N*64 bf16)
    // [9800064, 16200064)     y1       (N*64 bf16)
    //    cnt      @ 9800064   (N ints)      -- overlay, dead before y1 written
    //    fill     @ 10000128  (N ints)
    //    partials @ 10200192  (256 B)
    //    poff     @ 10200448  (256 B)
    // [16200064, 16331136)    pooled   (G*64 fp32)
    char* ws = (char*)d_ws;
    int*    row_ptr  = (int*)(ws);
    int*    colv     = (int*)(ws + 200064);
    bf16u*  y0       = (bf16u*)(ws + 3400064);
    bf16u*  y1       = (bf16u*)(ws + 9800064);
    int*    cnt      = (int*)(ws + 9800064);
    int*    fill     = (int*)(ws + 10000128);
    int*    partials = (int*)(ws + 10200192);
    int*    poff     = (int*)(ws + 10200448);
    float*  pooled   = (float*)(ws + 16200064);

    hipMemsetAsync(cnt, 0, 400128, stream);     // covers cnt + fill
    hipMemsetAsync(pooled, 0, (size_t)G * HID * sizeof(float), stream);

    int eb = (E + 255) / 256;
    int nch = (N + 1023) / 1024;                // scan chunks (49)
    k_count<<<eb, 256, 0, stream>>>(dst, cnt, E);
    k_scan1<<<nch, 256, 0, stream>>>(cnt, partials, N);
    k_scan2<<<1, 64, 0, stream>>>(partials, poff, nch);
    k_scan3<<<nch, 256, 0, stream>>>(cnt, poff, row_ptr, N, E);
    k_place<<<eb, 256, 0, stream>>>(src, dst, row_ptr, fill, colv, E);

    int nb = (N + 15) / 16;                     // 3125
    k_lin0<<<nb, 256, 0, stream>>>((const float2*)x, w0a, y0, N);
    k_agg0f<<<nb, 256, 0, stream>>>((const uint32*)y0, row_ptr, colv, eps0,
                                    b0a, w0b, b0b, w1a, y1, N);
    k_agg1<<<nb, 256, 0, stream>>>((const uint32*)y1, row_ptr, colv, eps1,
                                   b1a, w1b, b1b, batch, pooled, N);
    k_head<<<G, 64, 0, stream>>>(pooled, fcw, fcb, out);
}

// Round 9
// 304.840 us; speedup vs baseline: 1.2243x; 1.0484x over previous
//
#include <hip/hip_runtime.h>
#include <math.h>

#define IN_CH 128
#define HID 64
#define OUT_CH 10

typedef unsigned int uint32;
typedef unsigned short bf16u;

static __device__ inline bf16u f2bf(float f) {
    uint32 u = __float_as_uint(f);
    u += 0x7fff + ((u >> 16) & 1);          // round-nearest-even
    return (bf16u)(u >> 16);
}
static __device__ inline float bflo(uint32 u) {   // low bf16 of packed pair
    return __uint_as_float(u << 16);
}
static __device__ inline float bfhi(uint32 u) {   // high bf16 of packed pair
    return __uint_as_float(u & 0xffff0000u);
}

// neighbor-sum for one node: lanes (c2,h); h=0/1 halves take alternate nbrs.
// Deep 16-edge stanza keeps 8 y-loads in flight per lane for latency hiding.
static __device__ inline void gather_nbrs(
    const uint32* __restrict__ y32, const int* __restrict__ col,
    int rs, int re, int h, int c2, float& ax, float& ay)
{
    int j = rs;
    for (; j + 16 <= re; j += 16) {
        int s0 = col[j + h],      s1 = col[j + 2 + h];
        int s2 = col[j + 4 + h],  s3 = col[j + 6 + h];
        int s4 = col[j + 8 + h],  s5 = col[j + 10 + h];
        int s6 = col[j + 12 + h], s7 = col[j + 14 + h];
        uint32 u0 = y32[(long)s0 * 32 + c2];
        uint32 u1 = y32[(long)s1 * 32 + c2];
        uint32 u2 = y32[(long)s2 * 32 + c2];
        uint32 u3 = y32[(long)s3 * 32 + c2];
        uint32 u4 = y32[(long)s4 * 32 + c2];
        uint32 u5 = y32[(long)s5 * 32 + c2];
        uint32 u6 = y32[(long)s6 * 32 + c2];
        uint32 u7 = y32[(long)s7 * 32 + c2];
        ax += ((bflo(u0) + bflo(u1)) + (bflo(u2) + bflo(u3)))
            + ((bflo(u4) + bflo(u5)) + (bflo(u6) + bflo(u7)));
        ay += ((bfhi(u0) + bfhi(u1)) + (bfhi(u2) + bfhi(u3)))
            + ((bfhi(u4) + bfhi(u5)) + (bfhi(u6) + bfhi(u7)));
    }
    if (j + 8 <= re) {
        int sA = col[j + h],     sB = col[j + 2 + h];
        int sC = col[j + 4 + h], sD = col[j + 6 + h];
        uint32 uA = y32[(long)sA * 32 + c2];
        uint32 uB = y32[(long)sB * 32 + c2];
        uint32 uC = y32[(long)sC * 32 + c2];
        uint32 uD = y32[(long)sD * 32 + c2];
        ax += (bflo(uA) + bflo(uB)) + (bflo(uC) + bflo(uD));
        ay += (bfhi(uA) + bfhi(uB)) + (bfhi(uC) + bfhi(uD));
        j += 8;
    }
    for (; j + 2 <= re; j += 2) {
        int s = col[j + h];
        uint32 u = y32[(long)s * 32 + c2];
        ax += bflo(u); ay += bfhi(u);
    }
    if (j < re && h == 0) {
        uint32 u = y32[(long)col[j] * 32 + c2];
        ax += bflo(u); ay += bfhi(u);
    }
}

// ---------- CSR build: degree count ----------
__global__ __launch_bounds__(256) void k_count(
    const int* __restrict__ dst, int* __restrict__ cnt, int E)
{
    int e = blockIdx.x * 256 + threadIdx.x;
    if (e < E) atomicAdd(&cnt[dst[e]], 1);
}

// ---------- scan stage 1 ----------
__global__ __launch_bounds__(256) void k_scan1(
    const int* __restrict__ cnt, int* __restrict__ partials, int N)
{
    __shared__ int red[256];
    int tid = threadIdx.x;
    long base = (long)blockIdx.x * 1024 + tid * 4;
    int s = 0;
    #pragma unroll
    for (int i = 0; i < 4; i++) { long idx = base + i; if (idx < N) s += cnt[idx]; }
    red[tid] = s;
    __syncthreads();
    for (int off = 128; off; off >>= 1) {
        if (tid < off) red[tid] += red[tid + off];
        __syncthreads();
    }
    if (tid == 0) partials[blockIdx.x] = red[0];
}

// ---------- scan stage 2 ----------
__global__ __launch_bounds__(64) void k_scan2(
    const int* __restrict__ partials, int* __restrict__ poff, int nch)
{
    int lane = threadIdx.x;
    int carry = 0;
    for (int base = 0; base < nch; base += 64) {
        int i = base + lane;
        int v = (i < nch) ? partials[i] : 0;
        int incl = v;
        #pragma unroll
        for (int off = 1; off < 64; off <<= 1) {
            int t = __shfl_up(incl, off);
            if (lane >= off) incl += t;
        }
        if (i < nch) poff[i] = carry + incl - v;
        carry += __shfl(incl, 63);
    }
}

// ---------- scan stage 3 ----------
__global__ __launch_bounds__(256) void k_scan3(
    const int* __restrict__ cnt, const int* __restrict__ poff,
    int* __restrict__ row_ptr, int N, int E)
{
    __shared__ int lds[256];
    int tid = threadIdx.x;
    long base = (long)blockIdx.x * 1024 + tid * 4;
    int v[4]; int s = 0;
    #pragma unroll
    for (int i = 0; i < 4; i++) {
        long idx = base + i;
        v[i] = (idx < N) ? cnt[idx] : 0;
        s += v[i];
    }
    lds[tid] = s;
    __syncthreads();
    for (int off = 1; off < 256; off <<= 1) {
        int t = (tid >= off) ? lds[tid - off] : 0;
        __syncthreads();
        lds[tid] += t;
        __syncthreads();
    }
    int run = poff[blockIdx.x] + lds[tid] - s;
    #pragma unroll
    for (int i = 0; i < 4; i++) {
        long idx = base + i;
        if (idx < N) row_ptr[idx] = run;
        run += v[i];
    }
    if (blockIdx.x == 0 && tid == 0) row_ptr[N] = E;
}

// ---------- CSR build: place edges ----------
__global__ __launch_bounds__(256) void k_place(
    const int* __restrict__ src, const int* __restrict__ dst,
    const int* __restrict__ row_ptr, int* __restrict__ fill,
    int* __restrict__ col, int E)
{
    int e = blockIdx.x * 256 + threadIdx.x;
    if (e >= E) return;
    int d = dst[e];
    int pos = atomicAdd(&fill[d], 1);
    col[row_ptr[d] + pos] = src[e];
}

// ---------- dense GEMM: y0[N,64](bf16) = x[N,128] @ w0a[128,64] ----------
__global__ __launch_bounds__(256) void k_lin0(
    const float2* __restrict__ x2, const float* __restrict__ w,
    bf16u* __restrict__ y, int N)
{
    __shared__ uint32 lw[(IN_CH / 2) * HID];  // 16 KB packed
    __shared__ float t[16][IN_CH];            // 8 KB, per-wave rows
    int tid = threadIdx.x;
    for (int i = tid; i < (IN_CH / 2) * HID; i += 256) {
        int k2 = i >> 6, c = i & 63;
        lw[i] = (uint32)f2bf(w[(2 * k2) * HID + c]) |
                ((uint32)f2bf(w[(2 * k2 + 1) * HID + c]) << 16);
    }
    int wid = tid >> 6, c = tid & 63;
    int n0 = wid * 4;
    __syncthreads();
    for (long g0 = (long)blockIdx.x * 16; g0 < N; g0 += (long)gridDim.x * 16) {
        #pragma unroll
        for (int m = 0; m < 4; m++) {
            long node = g0 + n0 + m;
            if (node < N)
                *(float2*)&t[n0 + m][2 * c] = x2[node * 64 + c];
        }
        float a0 = 0.f, a1 = 0.f, a2 = 0.f, a3 = 0.f;
        #pragma unroll 8
        for (int k4 = 0; k4 < IN_CH / 4; k4++) {
            float4 t0 = *(const float4*)&t[n0 + 0][k4 * 4];
            float4 t1 = *(const float4*)&t[n0 + 1][k4 * 4];
            float4 t2 = *(const float4*)&t[n0 + 2][k4 * 4];
            float4 t3 = *(const float4*)&t[n0 + 3][k4 * 4];
            uint32 u01 = lw[(k4 * 2 + 0) * HID + c];
            uint32 u23 = lw[(k4 * 2 + 1) * HID + c];
            float w0 = bflo(u01), w1 = bfhi(u01);
            float w2 = bflo(u23), w3 = bfhi(u23);
            a0 = fmaf(t0.w, w3, fmaf(t0.z, w2, fmaf(t0.y, w1, fmaf(t0.x, w0, a0))));
            a1 = fmaf(t1.w, w3, fmaf(t1.z, w2, fmaf(t1.y, w1, fmaf(t1.x, w0, a1))));
            a2 = fmaf(t2.w, w3, fmaf(t2.z, w2, fmaf(t2.y, w1, fmaf(t2.x, w0, a2))));
            a3 = fmaf(t3.w, w3, fmaf(t3.z, w2, fmaf(t3.y, w1, fmaf(t3.x, w0, a3))));
        }
        float accv[4] = {a0, a1, a2, a3};
        #pragma unroll
        for (int m = 0; m < 4; m++) {
            long node = g0 + n0 + m;
            if (node < N) y[node * HID + c] = f2bf(accv[m]);
        }
    }
}

// ---------- layer-0 gather + MLP-b + fused lin1 ----------
// y1 = ( relu( relu((1+e)y0 + sum y0[nbr] + b0a) @ w0b + b0b ) ) @ w1a
__global__ __launch_bounds__(256, 7) void k_agg0f(
    const uint32* __restrict__ y32, const int* __restrict__ row_ptr,
    const int* __restrict__ col, const float* __restrict__ epsp,
    const float* __restrict__ ba, const float* __restrict__ wb,
    const float* __restrict__ bb, const float* __restrict__ w1a,
    bf16u* __restrict__ y1, int N)
{
    __shared__ uint32 lwb[(HID / 2) * HID];   // 8 KB packed
    __shared__ uint32 lw1[(HID / 2) * HID];   // 8 KB packed
    __shared__ float t[16][HID];              // 4 KB (t, then reused as h2)
    int tid = threadIdx.x;
    for (int i = tid; i < (HID / 2) * HID; i += 256) {
        int k2 = i >> 6, c = i & 63;
        lwb[i] = (uint32)f2bf(wb[(2 * k2) * HID + c]) |
                 ((uint32)f2bf(wb[(2 * k2 + 1) * HID + c]) << 16);
        lw1[i] = (uint32)f2bf(w1a[(2 * k2) * HID + c]) |
                 ((uint32)f2bf(w1a[(2 * k2 + 1) * HID + c]) << 16);
    }
    float e = 1.f + epsp[0];
    int wid = tid >> 6, lane = tid & 63;
    int c2 = lane & 31, h = lane >> 5;
    int c = lane;
    int n0 = wid * 4;
    float2 bav = ((const float2*)ba)[c2];
    float bbv = bb[c];
    __syncthreads();
    for (long g0 = (long)blockIdx.x * 16; g0 < N; g0 += (long)gridDim.x * 16) {
        for (int m = 0; m < 4; m++) {
            long node = g0 + n0 + m;
            float ax = 0.f, ay = 0.f;
            if (node < N) {
                int rs = row_ptr[node], re = row_ptr[node + 1];
                gather_nbrs(y32, col, rs, re, h, c2, ax, ay);
                if (h == 0) {
                    uint32 u = y32[node * 32 + c2];
                    ax = fmaf(e, bflo(u), ax); ay = fmaf(e, bfhi(u), ay);
                }
            }
            ax += __shfl_xor(ax, 32);
            ay += __shfl_xor(ay, 32);
            if (h == 0) {
                float2 v;
                v.x = fmaxf(ax + bav.x, 0.f);
                v.y = fmaxf(ay + bav.y, 0.f);
                *(float2*)&t[n0 + m][2 * c2] = v;
            }
        }
        // ---- M1: h2 = relu(t @ wb + bb); write back into t (wave-private)
        {
            float a0 = bbv, a1 = bbv, a2 = bbv, a3 = bbv;
            #pragma unroll 8
            for (int k4 = 0; k4 < HID / 4; k4++) {
                float4 t0 = *(const float4*)&t[n0 + 0][k4 * 4];
                float4 t1 = *(const float4*)&t[n0 + 1][k4 * 4];
                float4 t2 = *(const float4*)&t[n0 + 2][k4 * 4];
                float4 t3 = *(const float4*)&t[n0 + 3][k4 * 4];
                uint32 u01 = lwb[(k4 * 2 + 0) * HID + c];
                uint32 u23 = lwb[(k4 * 2 + 1) * HID + c];
                float w0 = bflo(u01), w1 = bfhi(u01);
                float w2 = bflo(u23), w3 = bfhi(u23);
                a0 = fmaf(t0.w, w3, fmaf(t0.z, w2, fmaf(t0.y, w1, fmaf(t0.x, w0, a0))));
                a1 = fmaf(t1.w, w3, fmaf(t1.z, w2, fmaf(t1.y, w1, fmaf(t1.x, w0, a1))));
                a2 = fmaf(t2.w, w3, fmaf(t2.z, w2, fmaf(t2.y, w1, fmaf(t2.x, w0, a2))));
                a3 = fmaf(t3.w, w3, fmaf(t3.z, w2, fmaf(t3.y, w1, fmaf(t3.x, w0, a3))));
            }
            t[n0 + 0][c] = fmaxf(a0, 0.f);
            t[n0 + 1][c] = fmaxf(a1, 0.f);
            t[n0 + 2][c] = fmaxf(a2, 0.f);
            t[n0 + 3][c] = fmaxf(a3, 0.f);
        }
        // ---- M2: y1 = h2 @ w1a
        {
            float a0 = 0.f, a1 = 0.f, a2 = 0.f, a3 = 0.f;
            #pragma unroll 8
            for (int k4 = 0; k4 < HID / 4; k4++) {
                float4 t0 = *(const float4*)&t[n0 + 0][k4 * 4];
                float4 t1 = *(const float4*)&t[n0 + 1][k4 * 4];
                float4 t2 = *(const float4*)&t[n0 + 2][k4 * 4];
                float4 t3 = *(const float4*)&t[n0 + 3][k4 * 4];
                uint32 u01 = lw1[(k4 * 2 + 0) * HID + c];
                uint32 u23 = lw1[(k4 * 2 + 1) * HID + c];
                float w0 = bflo(u01), w1 = bfhi(u01);
                float w2 = bflo(u23), w3 = bfhi(u23);
                a0 = fmaf(t0.w, w3, fmaf(t0.z, w2, fmaf(t0.y, w1, fmaf(t0.x, w0, a0))));
                a1 = fmaf(t1.w, w3, fmaf(t1.z, w2, fmaf(t1.y, w1, fmaf(t1.x, w0, a1))));
                a2 = fmaf(t2.w, w3, fmaf(t2.z, w2, fmaf(t2.y, w1, fmaf(t2.x, w0, a2))));
                a3 = fmaf(t3.w, w3, fmaf(t3.z, w2, fmaf(t3.y, w1, fmaf(t3.x, w0, a3))));
            }
            float accv[4] = {a0, a1, a2, a3};
            #pragma unroll
            for (int m = 0; m < 4; m++) {
                long node = g0 + n0 + m;
                if (node < N) y1[node * HID + c] = f2bf(accv[m]);
            }
        }
    }
}

// ---------- layer-1 gather + MLP-b + pooling ----------
__global__ __launch_bounds__(256, 7) void k_agg1(
    const uint32* __restrict__ y32, const int* __restrict__ row_ptr,
    const int* __restrict__ col, const float* __restrict__ epsp,
    const float* __restrict__ ba, const float* __restrict__ wb,
    const float* __restrict__ bb, const int* __restrict__ batch,
    float* __restrict__ pooled, int N)
{
    __shared__ uint32 lwb[(HID / 2) * HID];   // 8 KB packed
    __shared__ float t[16][HID];              // 4 KB
    int tid = threadIdx.x;
    for (int i = tid; i < (HID / 2) * HID; i += 256) {
        int k2 = i >> 6, c = i & 63;
        lwb[i] = (uint32)f2bf(wb[(2 * k2) * HID + c]) |
                 ((uint32)f2bf(wb[(2 * k2 + 1) * HID + c]) << 16);
    }
    float e = 1.f + epsp[0];
    int wid = tid >> 6, lane = tid & 63;
    int c2 = lane & 31, h = lane >> 5;
    int c = lane;
    int n0 = wid * 4;
    float2 bav = ((const float2*)ba)[c2];
    float bbv = bb[c];
    __syncthreads();
    for (long g0 = (long)blockIdx.x * 16; g0 < N; g0 += (long)gridDim.x * 16) {
        for (int m = 0; m < 4; m++) {
            long node = g0 + n0 + m;
            float ax = 0.f, ay = 0.f;
            if (node < N) {
                int rs = row_ptr[node], re = row_ptr[node + 1];
                gather_nbrs(y32, col, rs, re, h, c2, ax, ay);
                if (h == 0) {
                    uint32 u = y32[node * 32 + c2];
                    ax = fmaf(e, bflo(u), ax); ay = fmaf(e, bfhi(u), ay);
                }
            }
            ax += __shfl_xor(ax, 32);
            ay += __shfl_xor(ay, 32);
            if (h == 0) {
                float2 v;
                v.x = fmaxf(ax + bav.x, 0.f);
                v.y = fmaxf(ay + bav.y, 0.f);
                *(float2*)&t[n0 + m][2 * c2] = v;
            }
        }
        // M1: r = relu(t @ w1b + b1b), then pooled[batch] += r
        float a0 = bbv, a1 = bbv, a2 = bbv, a3 = bbv;
        #pragma unroll 8
        for (int k4 = 0; k4 < HID / 4; k4++) {
            float4 t0 = *(const float4*)&t[n0 + 0][k4 * 4];
            float4 t1 = *(const float4*)&t[n0 + 1][k4 * 4];
            float4 t2 = *(const float4*)&t[n0 + 2][k4 * 4];
            float4 t3 = *(const float4*)&t[n0 + 3][k4 * 4];
            uint32 u01 = lwb[(k4 * 2 + 0) * HID + c];
            uint32 u23 = lwb[(k4 * 2 + 1) * HID + c];
            float w0 = bflo(u01), w1 = bfhi(u01);
            float w2 = bflo(u23), w3 = bfhi(u23);
            a0 = fmaf(t0.w, w3, fmaf(t0.z, w2, fmaf(t0.y, w1, fmaf(t0.x, w0, a0))));
            a1 = fmaf(t1.w, w3, fmaf(t1.z, w2, fmaf(t1.y, w1, fmaf(t1.x, w0, a1))));
            a2 = fmaf(t2.w, w3, fmaf(t2.z, w2, fmaf(t2.y, w1, fmaf(t2.x, w0, a2))));
            a3 = fmaf(t3.w, w3, fmaf(t3.z, w2, fmaf(t3.y, w1, fmaf(t3.x, w0, a3))));
        }
        float accv[4] = {fmaxf(a0, 0.f), fmaxf(a1, 0.f), fmaxf(a2, 0.f), fmaxf(a3, 0.f)};
        long nodeA = g0 + n0;
        int nv = (int)((N - nodeA) < 4 ? (N - nodeA) : 4);
        if (nv > 0) {
            int bf = batch[nodeA], bl = batch[nodeA + nv - 1];
            if (bf == bl) {
                float s = 0.f;
                for (int n = 0; n < nv; n++) s += accv[n];
                atomicAdd(&pooled[(long)bf * HID + c], s);
            } else {
                for (int n = 0; n < nv; n++)
                    atomicAdd(&pooled[(long)batch[nodeA + n] * HID + c], accv[n]);
            }
        }
    }
}

// ---------- head: logits = pooled@fcw+fcb; log_softmax ----------
__global__ __launch_bounds__(64) void k_head(
    const float* __restrict__ pooled, const float* __restrict__ fcw,
    const float* __restrict__ fcb, float* __restrict__ out)
{
    int g = blockIdx.x;
    int l = threadIdx.x;
    float logit = -INFINITY;
    if (l < OUT_CH) {
        float acc = fcb[l];
        #pragma unroll
        for (int k = 0; k < HID; k++)
            acc = fmaf(pooled[g * HID + k], fcw[k * OUT_CH + l], acc);
        logit = acc;
    }
    float m = logit;
    #pragma unroll
    for (int off = 32; off; off >>= 1) m = fmaxf(m, __shfl_xor(m, off));
    float ex = (l < OUT_CH) ? expf(logit - m) : 0.0f;
    float s = ex;
    #pragma unroll
    for (int off = 32; off; off >>= 1) s += __shfl_xor(s, off);
    if (l < OUT_CH) out[g * OUT_CH + l] = logit - m - logf(s);
}

extern "C" void kernel_launch(void* const* d_in, const int* in_sizes, int n_in,
                              void* d_out, int out_size, void* d_ws, size_t ws_size,
                              hipStream_t stream) {
    const float* x    = (const float*)d_in[0];
    const int*   ei   = (const int*)d_in[1];
    const int*   batch= (const int*)d_in[2];
    const float* eps0 = (const float*)d_in[3];
    const float* w0a  = (const float*)d_in[4];
    const float* b0a  = (const float*)d_in[5];
    const float* w0b  = (const float*)d_in[6];
    const float* b0b  = (const float*)d_in[7];
    const float* eps1 = (const float*)d_in[8];
    const float* w1a  = (const float*)d_in[9];
    const float* b1a  = (const float*)d_in[10];
    const float* w1b  = (const float*)d_in[11];
    const float* b1b  = (const float*)d_in[12];
    const float* fcw  = (const float*)d_in[13];
    const float* fcb  = (const float*)d_in[14];
    float* out = (float*)d_out;

    const int N = in_sizes[0] / IN_CH;       // 50000
    const int E = in_sizes[1] / 2;           // 800000
    const int G = out_size / OUT_CH;         // 512
    const int* src = ei;
    const int* dst = ei + E;

    // workspace layout (bytes):
    // [0, 200064)             row_ptr  (N+1 ints)
    // [200064, 3400064)       col      (E ints)
    // [3400064, 9800064)      y0       (N*64 bf16)
    // [9800064, 16200064)     y1       (N*64 bf16)
    //    cnt      @ 9800064   (N ints)      -- overlay, dead before y1 written
    //    fill     @ 10000128  (N ints)
    //    partials @ 10200192  (256 B)
    //    poff     @ 10200448  (256 B)
    // [16200064, 16331136)    pooled   (G*64 fp32)
    char* ws = (char*)d_ws;
    int*    row_ptr  = (int*)(ws);
    int*    colv     = (int*)(ws + 200064);
    bf16u*  y0       = (bf16u*)(ws + 3400064);
    bf16u*  y1       = (bf16u*)(ws + 9800064);
    int*    cnt      = (int*)(ws + 9800064);
    int*    fill     = (int*)(ws + 10000128);
    int*    partials = (int*)(ws + 10200192);
    int*    poff     = (int*)(ws + 10200448);
    float*  pooled   = (float*)(ws + 16200064);

    hipMemsetAsync(cnt, 0, 400128, stream);     // covers cnt + fill
    hipMemsetAsync(pooled, 0, (size_t)G * HID * sizeof(float), stream);

    int eb = (E + 255) / 256;
    int nch = (N + 1023) / 1024;                // scan chunks (49)
    k_count<<<eb, 256, 0, stream>>>(dst, cnt, E);
    k_scan1<<<nch, 256, 0, stream>>>(cnt, partials, N);
    k_scan2<<<1, 64, 0, stream>>>(partials, poff, nch);
    k_scan3<<<nch, 256, 0, stream>>>(cnt, poff, row_ptr, N, E);
    k_place<<<eb, 256, 0, stream>>>(src, dst, row_ptr, fill, colv, E);

    int nb = (N + 15) / 16;                     // 3125
    k_lin0<<<nb, 256, 0, stream>>>((const float2*)x, w0a, y0, N);
    k_agg0f<<<nb, 256, 0, stream>>>((const uint32*)y0, row_ptr, colv, eps0,
                                    b0a, w0b, b0b, w1a, y1, N);
    k_agg1<<<nb, 256, 0, stream>>>((const uint32*)y1, row_ptr, colv, eps1,
                                   b1a, w1b, b1b, batch, pooled, N);
    k_head<<<G, 64, 0, stream>>>(pooled, fcw, fcb, out);
}